// Round 9
// baseline (80.937 us; speedup 1.0000x reference)
//
#include <hip/hip_runtime.h>
#include <math.h>

#define BB 4
#define TT 2048
#define DM 768
#define HD 64
#define NROW (BB*TT)   // 8192

typedef __attribute__((ext_vector_type(8))) short bf16x8;
typedef __attribute__((ext_vector_type(4))) float f32x4;

__device__ __forceinline__ unsigned short f2bf(float f) {
    unsigned int u = __float_as_uint(f);
    u += 0x7FFFu + ((u >> 16) & 1u);   // RNE
    return (unsigned short)(u >> 16);
}

// ---------------- Fused QKV projection ----------------
// Round-2 fp32 FMA compute (measured-fast) + LDS-bounce coalesced bf16 epilogue.
// grid 256 blocks x 256 threads; each block: 32 rows x (3x64) cols.
__global__ __launch_bounds__(256) void qkv_proj_kernel(
    const float* __restrict__ x,
    const float* __restrict__ Wq, const float* __restrict__ bq,
    const float* __restrict__ Wk, const float* __restrict__ bk,
    const float* __restrict__ Wv, const float* __restrict__ bv,
    unsigned short* __restrict__ qo, unsigned short* __restrict__ ko,
    unsigned short* __restrict__ vT)
{
    __shared__ float xs[32][68];
    __shared__ float wt[64][196];
    const int tid = threadIdx.x;
    const int rg = tid >> 4;      // 0..15 -> rows 2rg, 2rg+1
    const int cg = tid & 15;      // 0..15 -> cols 4cg..4cg+3 of each matrix
    const int row0 = blockIdx.x * 32;

    float acc[2][3][4];
    #pragma unroll
    for (int i = 0; i < 2; ++i)
        #pragma unroll
        for (int m = 0; m < 3; ++m)
            #pragma unroll
            for (int e = 0; e < 4; ++e) acc[i][m][e] = 0.f;

    for (int kb = 0; kb < DM/64; ++kb) {
        __syncthreads();
        // stage x tile: 32 x 64
        #pragma unroll
        for (int p = 0; p < 2; ++p) {
            int f4 = tid + 256*p;
            int r = f4 >> 4;
            int c = (f4 & 15) << 2;
            *(float4*)(&xs[r][c]) = *(const float4*)(x + (size_t)(row0 + r)*DM + kb*64 + c);
        }
        // stage W tile: 64 x 192 (q|k|v)
        #pragma unroll
        for (int p = 0; p < 12; ++p) {
            int f4 = tid + 256*p;
            int c4 = f4 % 48;            // float4-column 0..47
            int r  = f4 / 48;            // 0..63
            int mat = c4 >> 4;           // 0..2
            int cm  = (c4 & 15) << 2;    // col within one matrix
            const float* Wp = (mat == 0) ? Wq : ((mat == 1) ? Wk : Wv);
            *(float4*)(&wt[r][c4*4]) = *(const float4*)(Wp + (size_t)(kb*64 + r)*HD + cm);
        }
        __syncthreads();
        // compute: 64 kk per chunk
        #pragma unroll
        for (int ks = 0; ks < 16; ++ks) {
            float4 a0 = *(const float4*)(&xs[2*rg+0][ks*4]);
            float4 a1 = *(const float4*)(&xs[2*rg+1][ks*4]);
            #pragma unroll
            for (int kk = 0; kk < 4; ++kk) {
                float av0 = ((const float*)&a0)[kk];
                float av1 = ((const float*)&a1)[kk];
                #pragma unroll
                for (int m = 0; m < 3; ++m) {
                    float4 b = *(const float4*)(&wt[ks*4+kk][4*cg + 64*m]);
                    #pragma unroll
                    for (int e = 0; e < 4; ++e) {
                        acc[0][m][e] = fmaf(av0, ((const float*)&b)[e], acc[0][m][e]);
                        acc[1][m][e] = fmaf(av1, ((const float*)&b)[e], acc[1][m][e]);
                    }
                }
            }
        }
    }

    // ---- epilogue: bias + bf16 pack into LDS (reusing wt), coalesced stores ----
    const float4 biq = *(const float4*)(bq + 4*cg);
    const float4 bik = *(const float4*)(bk + 4*cg);
    const float4 biv = *(const float4*)(bv + 4*cg);
    __syncthreads();                       // all waves done reading wt/xs
    unsigned short* sqk = (unsigned short*)&wt[0][0];    // [2][32][72] = 4608
    unsigned short* sv  = sqk + 2*32*72;                 // [64][36]    = 2304
    #pragma unroll
    for (int i = 0; i < 2; ++i) {
        const int rr = 2*rg + i;
        ushort4 qv, kv;
        qv.x = f2bf((acc[i][0][0] + biq.x) * 0.125f);
        qv.y = f2bf((acc[i][0][1] + biq.y) * 0.125f);
        qv.z = f2bf((acc[i][0][2] + biq.z) * 0.125f);
        qv.w = f2bf((acc[i][0][3] + biq.w) * 0.125f);
        kv.x = f2bf(acc[i][1][0] + bik.x);
        kv.y = f2bf(acc[i][1][1] + bik.y);
        kv.z = f2bf(acc[i][1][2] + bik.z);
        kv.w = f2bf(acc[i][1][3] + bik.w);
        *(ushort4*)&sqk[(size_t)(0*32 + rr)*72 + 4*cg] = qv;
        *(ushort4*)&sqk[(size_t)(1*32 + rr)*72 + 4*cg] = kv;
        #pragma unroll
        for (int e = 0; e < 4; ++e)
            sv[(size_t)(4*cg + e)*36 + rr] = f2bf(acc[i][2][e] + ((const float*)&biv)[e]);
    }
    __syncthreads();
    // q/k: 512 row-chunks of 8 cols; thread handles 2
    #pragma unroll
    for (int p = 0; p < 2; ++p) {
        int c = tid + 256*p;
        int mqk = c >> 8;                 // 0=q, 1=k
        int rr  = (c >> 3) & 31;
        int c8  = (c & 7) * 8;
        ushort4 a  = *(const ushort4*)&sqk[(size_t)(mqk*32 + rr)*72 + c8];
        ushort4 b2 = *(const ushort4*)&sqk[(size_t)(mqk*32 + rr)*72 + c8 + 4];
        unsigned short* op = (mqk == 0) ? qo : ko;
        *(ushort4*)(op + (size_t)(row0 + rr)*HD + c8)     = a;
        *(ushort4*)(op + (size_t)(row0 + rr)*HD + c8 + 4) = b2;
    }
    // vT: 64 cols x 32 t; thread handles 8 t of one col
    {
        const int h  = tid >> 2;
        const int tg = (tid & 3) * 8;
        const int b  = row0 >> 11;
        const int t0 = row0 & 2047;
        ushort4 a  = *(const ushort4*)&sv[(size_t)h*36 + tg];
        ushort4 b2 = *(const ushort4*)&sv[(size_t)h*36 + tg + 4];
        *(ushort4*)(vT + ((size_t)b*HD + h)*TT + t0 + tg)     = a;
        *(ushort4*)(vT + ((size_t)b*HD + h)*TT + t0 + tg + 4) = b2;
    }
}

// -------- Flash attention: bf16 MFMA, in-block 4-way key split (unchanged) --------
__global__ __launch_bounds__(256) void attn_mfma_kernel(
    const unsigned short* __restrict__ qb_, const unsigned short* __restrict__ kb_,
    const unsigned short* __restrict__ vt_, float* __restrict__ out)
{
    __shared__ unsigned short plds[4][16][40];
    __shared__ float olds[4][16][66];
    __shared__ float mlds[4][16][2];

    const int tid  = threadIdx.x;
    const int wv   = tid >> 6;
    const int lane = tid & 63;
    const int q15  = lane & 15;
    const int g    = lane >> 4;

    const int bx = blockIdx.x;
    const int b  = bx & 3;
    const int qt = (TT/16 - 1) - (bx >> 2);
    const int qbase = qt * 16;
    const int nk = qbase + 16;

    const unsigned short* qp = qb_ + (size_t)b*TT*HD;
    const unsigned short* kp = kb_ + (size_t)b*TT*HD;
    const unsigned short* vp = vt_ + (size_t)b*HD*TT;

    bf16x8 qf[2];
    #pragma unroll
    for (int c = 0; c < 2; ++c)
        qf[c] = *(const bf16x8*)(qp + (size_t)(qbase + q15)*HD + 32*c + 8*g);

    f32x4 accv[4];
    #pragma unroll
    for (int h = 0; h < 4; ++h) accv[h] = (f32x4){0.f, 0.f, 0.f, 0.f};
    float m = -INFINITY, l = 0.f;

    const int ck = ((nk + 127) >> 7) << 5;
    const int kstart = wv * ck;
    const int kend = min(kstart + ck, nk);

    for (int k0 = kstart; k0 < kend; k0 += 32) {
        bf16x8 vf[4];
        #pragma unroll
        for (int h = 0; h < 4; ++h)
            vf[h] = *(const bf16x8*)(vp + (size_t)(16*h + q15)*TT + k0 + 8*g);
        bf16x8 kf[2][2];
        #pragma unroll
        for (int t = 0; t < 2; ++t)
            #pragma unroll
            for (int c = 0; c < 2; ++c)
                kf[t][c] = *(const bf16x8*)(kp + (size_t)(k0 + 16*t + q15)*HD + 32*c + 8*g);

        f32x4 st[2];
        #pragma unroll
        for (int t = 0; t < 2; ++t) {
            f32x4 z = {0.f, 0.f, 0.f, 0.f};
            st[t] = __builtin_amdgcn_mfma_f32_16x16x32_bf16(kf[t][0], qf[0], z, 0, 0, 0);
            st[t] = __builtin_amdgcn_mfma_f32_16x16x32_bf16(kf[t][1], qf[1], st[t], 0, 0, 0);
        }
        if (k0 + 31 > qbase) {
            int qabs = qbase + q15;
            #pragma unroll
            for (int t = 0; t < 2; ++t)
                #pragma unroll
                for (int r = 0; r < 4; ++r)
                    if (k0 + 16*t + 4*g + r > qabs) st[t][r] = -INFINITY;
        }
        float pmax = st[0][0];
        #pragma unroll
        for (int t = 0; t < 2; ++t)
            #pragma unroll
            for (int r = 0; r < 4; ++r) pmax = fmaxf(pmax, st[t][r]);
        pmax = fmaxf(pmax, __shfl_xor(pmax, 16));
        pmax = fmaxf(pmax, __shfl_xor(pmax, 32));
        float mnew = fmaxf(m, pmax);
        float mc = fmaxf(mnew, -1e30f);
        float alpha = __expf(m - mc);
        float p[2][4];
        float psum = 0.f;
        #pragma unroll
        for (int t = 0; t < 2; ++t)
            #pragma unroll
            for (int r = 0; r < 4; ++r) {
                p[t][r] = __expf(st[t][r] - mc);
                psum += p[t][r];
            }
        psum += __shfl_xor(psum, 16);
        psum += __shfl_xor(psum, 32);
        l = l * alpha + psum;
        m = mnew;
        float av[4];
        #pragma unroll
        for (int r = 0; r < 4; ++r) av[r] = __shfl(alpha, 4*g + r);
        #pragma unroll
        for (int h = 0; h < 4; ++h)
            #pragma unroll
            for (int r = 0; r < 4; ++r) accv[h][r] *= av[r];
        #pragma unroll
        for (int t = 0; t < 2; ++t) {
            ushort4 pk;
            pk.x = f2bf(p[t][0]); pk.y = f2bf(p[t][1]);
            pk.z = f2bf(p[t][2]); pk.w = f2bf(p[t][3]);
            *(ushort4*)&plds[wv][q15][16*t + 4*g] = pk;
        }
        bf16x8 pa = *(const bf16x8*)&plds[wv][q15][8*g];
        #pragma unroll
        for (int h = 0; h < 4; ++h)
            accv[h] = __builtin_amdgcn_mfma_f32_16x16x32_bf16(pa, vf[h], accv[h], 0, 0, 0);
    }

    #pragma unroll
    for (int h = 0; h < 4; ++h)
        #pragma unroll
        for (int r = 0; r < 4; ++r)
            olds[wv][4*g + r][16*h + q15] = accv[h][r];
    if (g == 0) { mlds[wv][q15][0] = m; mlds[wv][q15][1] = l; }
    __syncthreads();

    {
        int qq = tid >> 4;
        int c4 = (tid & 15) << 2;
        float mw[4], lw[4];
        #pragma unroll
        for (int w = 0; w < 4; ++w) { mw[w] = mlds[w][qq][0]; lw[w] = mlds[w][qq][1]; }
        float M = fmaxf(fmaxf(mw[0], mw[1]), fmaxf(mw[2], mw[3]));
        float Mc = fmaxf(M, -1e30f);
        float ww[4], ltot = 0.f;
        #pragma unroll
        for (int w = 0; w < 4; ++w) { ww[w] = __expf(mw[w] - Mc); ltot += ww[w]*lw[w]; }
        float invl = 1.f / ltot;
        float4 o;
        #pragma unroll
        for (int e = 0; e < 4; ++e) {
            float s = 0.f;
            #pragma unroll
            for (int w = 0; w < 4; ++w) s += ww[w] * olds[w][qq][c4 + e];
            ((float*)&o)[e] = s * invl;
        }
        *(float4*)(out + ((size_t)b*TT + qbase + qq)*HD + c4) = o;
    }
}

extern "C" void kernel_launch(void* const* d_in, const int* in_sizes, int n_in,
                              void* d_out, int out_size, void* d_ws, size_t ws_size,
                              hipStream_t stream) {
    const float* x  = (const float*)d_in[0];
    const float* Wq = (const float*)d_in[1];
    const float* bq = (const float*)d_in[2];
    const float* Wk = (const float*)d_in[3];
    const float* bk = (const float*)d_in[4];
    const float* Wv = (const float*)d_in[5];
    const float* bv = (const float*)d_in[6];
    float* out = (float*)d_out;

    unsigned short* qbf = (unsigned short*)d_ws;
    unsigned short* kbf = qbf + (size_t)NROW*HD;
    unsigned short* vT  = kbf + (size_t)NROW*HD;

    qkv_proj_kernel<<<NROW/32, 256, 0, stream>>>(x, Wq, bq, Wk, bk, Wv, bv, qbf, kbf, vT);
    attn_mfma_kernel<<<dim3(TT/16 * BB), 256, 0, stream>>>(qbf, kbf, vT, out);
}